// Round 10
// baseline (808.384 us; speedup 1.0000x reference)
//
#include <hip/hip_runtime.h>
#include <cstdint>
#include <cstddef>

// ---------------------------------------------------------------------------
// PiFormerFFN R13: 256x256 tile, 8-wave, B direct-from-global (VGPR), A
// double-buffered in 64 KiB LDS. ONE barrier + one vmcnt(0) gate per tile.
//   out = gelu_q(x @ W1^T) @ W2^T
//
// R12 failed correctness: b23(t+1) was loaded BEFORE q3 consumed b23(t)
// (source-level WAR -- q3 read the new values). R13 reorders S3:
//   load b01(t+1)+af(t+1) (not read by q3) -> q3 on OLD b23 -> load b23(t+1)
//   -> stage A(t+2).
//
// Perf model (R7/R11 data): per CU per tile MFMA ~2483 cyc, LDS ~2600 cyc;
// barrier-lockstep schedules measure ~the SUM (phases of all 8 waves align:
// LDS-burst then MFMA-burst). R13: (a) B via L2->VGPR cuts LDS demand to
// ~1800 cyc, (b) 1 barrier/tile lets waves' read/MFMA phases slide.
//
// Per-tile schedule:
//   S0: q0 (af x b01)                       [af,b01,b23 from S3(t-1)/prologue]
//   S1: read ah(t) ds[8]; q1 (af x b23)
//   S2: q2 (ah x b01)
//   S3: [s1] gate vmcnt(0); BAR; read af(t+1) ds[8]; load b01(t+1) glb[4]
//       q3 (ah x b23-old)
//       [s1] load b23(t+1) glb[4]; sched_barrier; [s2] stage A(t+2) dma[4]
// Race-freedom (order-independent):
//   - gate(t)=vmcnt(0) drains stage A(t+1) (issued S3(t-1)) for this wave;
//     BAR => for all waves, before any af(t+1) ds_read. Full-tile flight
//     (S3(t-1)->S3(t) ~= 1 tile >> HBM latency) makes the gate ~free.
//   - stage A(t+2)->buf[t&1]: every wave issued q2 (operand-waited on its
//     ah(t) reads of buf[t&1]) before reaching the S3 BAR.
//   - All B-register hazards are SSA-visible (compiler renames if needed).
//   - Tail: t=NT-2 skips stage; t=NT-1 skips S3 head. Nothing outstanding at
//     epilogue.
// Packed layout (R5, proven): per [R,K]: panel p=row/256, ktile t=k/64, half
//   h=(row%256)/128 -> 16 KiB region of 16x32 subtiles (1 KiB), st_16x32
//   swizzle (byte ^= ((byte>>9)&1)<<5) pre-applied in global memory.
// ---------------------------------------------------------------------------

typedef __bf16 bf16_t;
typedef bf16_t bf16x8 __attribute__((ext_vector_type(8)));
typedef float  floatx4 __attribute__((ext_vector_type(4)));

#define AS1 __attribute__((address_space(1)))
#define AS3 __attribute__((address_space(3)))

__device__ __forceinline__ void async_cp16(const void* g, void* l) {
    __builtin_amdgcn_global_load_lds((const AS1 void*)g, (AS3 void*)l, 16, 0, 0);
}

// tanh-approx gelu: gelu = x * (1 - 1/(1+e^{2u})), u = k0*(x + k1*x^3)
__device__ __forceinline__ float gelu_fast(float x) {
    const float C0 = 1.5957691216057308f;   // 2*sqrt(2/pi)
    const float C1 = 0.0713548163f;         // C0 * 0.044715
    float u2 = x * fmaf(C1, x * x, C0);
    float e  = __expf(u2);
    float r  = __builtin_amdgcn_rcpf(1.0f + e);
    return x * (1.0f - r);
}

// fp32 [R,K] row-major -> packed+swizzled bf16. One thread per 16B chunk.
// tshift = log2(K/64).
__global__ __launch_bounds__(256)
void cvt_pack_swz(const float* __restrict__ src, bf16_t* __restrict__ dst,
                  int K, int tshift)
{
    const size_t   oc = (size_t)blockIdx.x * 256 + threadIdx.x;  // 16B chunk
    const uint32_t ho = ((uint32_t)oc & 1023u) * 16u;  // phys byte in half-tile
    const size_t   region = oc >> 10;                  // 16 KiB half-tile index
    const int      h  = (int)(region & 1);
    const size_t   pt = region >> 1;
    const int      t  = (int)(pt & ((1u << tshift) - 1));
    const size_t   p  = pt >> tshift;
    // physical -> logical (involution)
    const uint32_t L = ho ^ (((ho >> 9) & 1u) << 5);
    const int      s = (int)(L >> 10);                 // subtile 0..15
    const uint32_t u = L & 1023u;
    const size_t   row = p * 256 + (size_t)(h * 128 + (s >> 1) * 16 + (int)(u >> 6));
    const int      k   = (t << 6) + (s & 1) * 32 + (int)((u & 63u) >> 1);
    const float* sp = src + row * (size_t)K + k;
    float4 a = *(const float4*)sp;
    float4 b = *(const float4*)(sp + 4);
    bf16x8 o;
    o[0] = (bf16_t)a.x; o[1] = (bf16_t)a.y; o[2] = (bf16_t)a.z; o[3] = (bf16_t)a.w;
    o[4] = (bf16_t)b.x; o[5] = (bf16_t)b.y; o[6] = (bf16_t)b.z; o[7] = (bf16_t)b.w;
    *(bf16x8*)(dst + oc * 8) = o;
}

// C = A * B^T, A/B in packed+swizzled layout. A via LDS, B direct-global.
template<bool ACT, typename OutT>
__global__ __launch_bounds__(512, 2)
void gemm256(const bf16_t* __restrict__ A, const bf16_t* __restrict__ B,
             OutT* __restrict__ C, int M, int N, int K, int nbxs)
{
    __shared__ __align__(16) bf16_t lds[32768];        // 64 KiB (A only)
    char* const ldsb = (char*)lds;

    const int NT  = K >> 6;                            // K-tiles (BK=64)
    const int id  = blockIdx.x;
    const int nwg = gridDim.x;
    // bijective XCD swizzle (nwg % 8 == 0 for both GEMMs)
    const int sw = (id & 7) * (nwg >> 3) + (id >> 3);
    const int by = sw >> nbxs;
    const int bx = sw & ((1 << nbxs) - 1);

    const int tid  = threadIdx.x;
    const int lane = tid & 63;
    const int wave = tid >> 6;
    const int wm = wave >> 2;                          // 0..1: M-half
    const int wn = wave & 3;                           // 0..3: N-quarter

    const bf16_t* const Ap = A + (size_t)by * NT * 16384;   // 256-row panel
    const char*  const Bpb = (const char*)(B + (size_t)bx * NT * 16384);

    // per-lane swizzled frag offset: logical (lane&15)*64 + (lane>>4)*16
    uint32_t lsw = (uint32_t)(((lane & 15) << 6) + ((lane >> 4) << 4));
    lsw ^= ((lsw >> 9) & 1u) << 5;

    const uint32_t aBase  = (uint32_t)wm << 14;        // wave's A half in buf
    const uint32_t bHalf  = (uint32_t)(wn >> 1) << 14; // wave's B half (global)
    const int      bSub   = (wn & 1) * 4;              // col-subtile offset

    // B frag address in packed global memory (bytes)
    auto bfrag = [&](int t, int fn, int ks) -> const bf16x8* {
        return (const bf16x8*)(Bpb + (size_t)t * 32768 + bHalf
                               + (uint32_t)((((bSub + fn) << 1) + ks) << 10) + lsw);
    };

    floatx4 acc[8][4];
    #pragma unroll
    for (int i = 0; i < 8; ++i)
      #pragma unroll
      for (int j = 0; j < 4; ++j)
        acc[i][j] = (floatx4)0.0f;

    // stage A half j of K-tile t: 2 x global_load_lds(16B)/thread, linear.
    auto stageA = [&](int t, int j) {
        const bf16_t* g = Ap + (size_t)t * 16384 + (size_t)j * 8192;
        char* l = ldsb + (((t & 1) << 15) + (j << 14));
        async_cp16((const char*)g + tid * 16, l + tid * 16);
        async_cp16((const char*)g + 8192 + tid * 16, l + 8192 + tid * 16);
    };

    // prologue: stage A(0), A(1); full drain (once); read af(0); load b(0).
    stageA(0, 0); stageA(0, 1); stageA(1, 0); stageA(1, 1);
    asm volatile("s_waitcnt vmcnt(0)" ::: "memory");   // A(0),A(1) landed
    __builtin_amdgcn_s_barrier();
    bf16x8 b01[2][2], b23[2][2], af[4][2];
    {
        const char* aB0 = ldsb + aBase;
        #pragma unroll
        for (int fm = 0; fm < 4; ++fm)
          #pragma unroll
          for (int ks = 0; ks < 2; ++ks)
            af[fm][ks] = *(const bf16x8*)(aB0 + ((((fm << 1) + ks) << 10) | lsw));
    }
    #pragma unroll
    for (int fn = 0; fn < 2; ++fn)
      #pragma unroll
      for (int ks = 0; ks < 2; ++ks) {
        b01[fn][ks] = *bfrag(0, fn, ks);
        b23[fn][ks] = *bfrag(0, 2 + fn, ks);
      }

    for (int t = 0; t < NT; ++t) {
        const char* aB = ldsb + ((t & 1) << 15) + aBase;
        const bool s1 = (t + 1 < NT);
        const bool s2 = (t + 2 < NT);

        // ---- S0: q0 = af x b01 (all operands pre-loaded)
        __builtin_amdgcn_s_setprio(1);
        #pragma unroll
        for (int ks = 0; ks < 2; ++ks)
          #pragma unroll
          for (int fm = 0; fm < 4; ++fm)
            #pragma unroll
            for (int fn = 0; fn < 2; ++fn)
              acc[fm][fn] = __builtin_amdgcn_mfma_f32_16x16x32_bf16(
                  af[fm][ks], b01[fn][ks], acc[fm][fn], 0, 0, 0);
        __builtin_amdgcn_s_setprio(0);

        // ---- S1: read ah(t) from LDS; q1 = af x b23
        bf16x8 ah[4][2];
        #pragma unroll
        for (int fm = 0; fm < 4; ++fm)
          #pragma unroll
          for (int ks = 0; ks < 2; ++ks)
            ah[fm][ks] = *(const bf16x8*)(aB + (((((4 + fm) << 1) + ks) << 10) | lsw));
        __builtin_amdgcn_s_setprio(1);
        #pragma unroll
        for (int ks = 0; ks < 2; ++ks)
          #pragma unroll
          for (int fm = 0; fm < 4; ++fm)
            #pragma unroll
            for (int fn = 0; fn < 2; ++fn)
              acc[fm][2 + fn] = __builtin_amdgcn_mfma_f32_16x16x32_bf16(
                  af[fm][ks], b23[fn][ks], acc[fm][2 + fn], 0, 0, 0);
        __builtin_amdgcn_s_setprio(0);

        // ---- S2: q2 = ah x b01
        __builtin_amdgcn_s_setprio(1);
        #pragma unroll
        for (int ks = 0; ks < 2; ++ks)
          #pragma unroll
          for (int fm = 0; fm < 4; ++fm)
            #pragma unroll
            for (int fn = 0; fn < 2; ++fn)
              acc[4 + fm][fn] = __builtin_amdgcn_mfma_f32_16x16x32_bf16(
                  ah[fm][ks], b01[fn][ks], acc[4 + fm][fn], 0, 0, 0);
        __builtin_amdgcn_s_setprio(0);

        // ---- S3 head: gate; BAR; read af(t+1); load b01(t+1)
        //      (q3 reads neither af nor b01 -- safe before it)
        if (s1) {
            asm volatile("s_waitcnt vmcnt(0)" ::: "memory");  // order-indep gate
            __builtin_amdgcn_s_barrier();
            const char* aBn = ldsb + (((t + 1) & 1) << 15) + aBase;
            #pragma unroll
            for (int fm = 0; fm < 4; ++fm)
              #pragma unroll
              for (int ks = 0; ks < 2; ++ks)
                af[fm][ks] = *(const bf16x8*)(aBn + ((((fm << 1) + ks) << 10) | lsw));
            #pragma unroll
            for (int fn = 0; fn < 2; ++fn)
              #pragma unroll
              for (int ks = 0; ks < 2; ++ks)
                b01[fn][ks] = *bfrag(t + 1, fn, ks);
        }

        // ---- q3 = ah x b23 (OLD b23 -- consumed before reload below)
        __builtin_amdgcn_s_setprio(1);
        #pragma unroll
        for (int ks = 0; ks < 2; ++ks)
          #pragma unroll
          for (int fm = 0; fm < 4; ++fm)
            #pragma unroll
            for (int fn = 0; fn < 2; ++fn)
              acc[4 + fm][2 + fn] = __builtin_amdgcn_mfma_f32_16x16x32_bf16(
                  ah[fm][ks], b23[fn][ks], acc[4 + fm][2 + fn], 0, 0, 0);
        __builtin_amdgcn_s_setprio(0);

        // ---- S3 tail: load b23(t+1); then stage A(t+2)
        if (s1) {
            #pragma unroll
            for (int fn = 0; fn < 2; ++fn)
              #pragma unroll
              for (int ks = 0; ks < 2; ++ks)
                b23[fn][ks] = *bfrag(t + 1, 2 + fn, ks);
            __builtin_amdgcn_sched_barrier(0);   // B loads BEFORE stage DMA
            if (s2) { stageA(t + 2, 0); stageA(t + 2, 1); }
        }
    }

    if constexpr (ACT) {
        // Fused quant+gelu; repack into act's packed+swizzled layout in TWO
        // 64 KiB passes. Wave (wm,wn) output 128x64 == one 16 KiB region:
        // panel by, ktile bx*4+wn, half wm. Pass ph handles fm in
        // {4ph..4ph+3} == phys bytes [ph*8192, +8192) of the region.
        const int nkt2 = N >> 6;
        bf16_t* const Cb = (bf16_t*)C;
        const uint32_t slot = (uint32_t)(wn * 2 + wm) << 13;   // 8 KiB slot
        #pragma unroll
        for (int ph = 0; ph < 2; ++ph) {
            __syncthreads();
            #pragma unroll
            for (int f4 = 0; f4 < 4; ++f4) {
              const int fm = 4 * ph + f4;
              #pragma unroll
              for (int fn = 0; fn < 4; ++fn)
                #pragma unroll
                for (int r = 0; r < 4; ++r) {
                    float h = acc[fm][fn][r];
                    float q = rintf(h * 10.0f);      // round half-to-even
                    q = fminf(fmaxf(q, -32768.0f), 32767.0f);
                    h = gelu_fast(q * 0.1f);
                    uint32_t L = ((uint32_t)((fm << 1) + (fn >> 1)) << 10)
                               + (uint32_t)((((lane >> 4) << 2) + r) << 6)
                               + (uint32_t)((((fn & 1) << 4) + (lane & 15)) << 1);
                    uint32_t P = (L & 8191u) ^ (((L >> 9) & 1u) << 5);
                    *(bf16_t*)(ldsb + slot + P) = (bf16_t)h;
                }
            }
            __syncthreads();
            // copyout: 8 slots x 8 KiB, contiguous global runs.
            #pragma unroll
            for (int it = 0; it < 8; ++it) {
                const int ch = it * 512 + tid;       // 0..4095
                const int s  = ch >> 9;              // slot 0..7
                const int c  = ch & 511;
                const size_t gr = ((size_t)by * nkt2 + (size_t)(bx * 4)
                                   + (s >> 1)) * 2 + (size_t)(s & 1);
                bf16x8 v = *(const bf16x8*)(ldsb + (size_t)ch * 16);
                *(bf16x8*)((char*)Cb + gr * 16384 + (size_t)ph * 8192
                           + (size_t)c * 16) = v;
            }
        }
    } else {
        // Row-major fp32 stores (quarter-wave writes 64B contiguous).
        const int r0 = by * 256 + wm * 128;
        const int c0 = bx * 256 + wn * 64;
        #pragma unroll
        for (int fm = 0; fm < 8; ++fm)
          #pragma unroll
          for (int fn = 0; fn < 4; ++fn) {
            const int col = c0 + fn * 16 + (lane & 15);
            #pragma unroll
            for (int r = 0; r < 4; ++r) {
              const int row = r0 + fm * 16 + ((lane >> 4) << 2) + r;
              C[(size_t)row * N + col] = (OutT)acc[fm][fn][r];
            }
          }
    }
}

extern "C" void kernel_launch(void* const* d_in, const int* in_sizes, int n_in,
                              void* d_out, int out_size, void* d_ws, size_t ws_size,
                              hipStream_t stream)
{
    const int M  = 8192;   // BATCH*SEQ
    const int DM = 2048;   // d_model
    const int DF = 8192;   // d_ff

    const float* x  = (const float*)d_in[0];
    const float* W1 = (const float*)d_in[1];
    const float* W2 = (const float*)d_in[2];
    float* out = (float*)d_out;

    bf16_t* xb  = (bf16_t*)d_ws;                      // packed [M,DM]
    bf16_t* w1b = xb  + (size_t)M  * DM;              // packed [DF,DM]
    bf16_t* w2b = w1b + (size_t)DF * DM;              // packed [DM,DF]
    bf16_t* act = w2b + (size_t)DM * DF;              // packed [M,DF]

    // converters: one thread per 16B output chunk; tshift = log2(K/64)
    cvt_pack_swz<<<8192, 256, 0, stream>>>(x,  xb,  DM, 5);
    cvt_pack_swz<<<8192, 256, 0, stream>>>(W1, w1b, DM, 5);
    cvt_pack_swz<<<8192, 256, 0, stream>>>(W2, w2b, DF, 7);

    // GEMM1 + fused quant/gelu: act = pack(gelu_q(xb @ w1b^T)); grid 32x32
    gemm256<true, bf16_t><<<dim3(1024), 512, 0, stream>>>(xb, w1b, act, M, DF, DM, 5);
    // GEMM2: out = act @ w2b^T; grid 32x8 = 256
    gemm256<false, float><<<dim3(256), 512, 0, stream>>>(act, w2b, out, M, DM, DF, 3);
}

// Round 11
// 699.150 us; speedup vs baseline: 1.1562x; 1.1562x over previous
//
#include <hip/hip_runtime.h>
#include <cstdint>
#include <cstddef>

// ---------------------------------------------------------------------------
// PiFormerFFN R14: 128x128 tile, 512 threads (8 waves of 32x64), 64 KiB LDS
// => TWO blocks per CU (16 waves, 4/SIMD). Cross-block TLP fills the
// barrier/gate bubbles that capped all 1-block/CU schedules at <=44% MfmaUtil
// (R5-R13 ledger). Simple 1-barrier/tile K-loop; overlap comes from the
// co-resident block, not intra-wave scheduling.
//   out = gelu_q(x @ W1^T) @ W2^T
//
// Resources/block: LDS 64 KiB (2buf x {A 16K, B 16K}); regs/wave ~110
// (acc 32 + frags 48 + addr) < 128 => launch_bounds(512,4) without spills
// (R8's death was 128 acc regs at the 256 tile; this tile has 32).
//
// K-loop per tile t: {stage(t+1) [4 cp16] | 12 ds_read(t) | 16 MFMA |
//   vmcnt(0) | BAR}. Race-freedom: stage(t+1) targets buf[(t+1)&1], last
//   read in tile t-1; those reads were serviced (operand waits) before each
//   wave's MFMA(t-1) issued, which precedes BAR(t-1), which precedes this
//   stage for ALL waves. vmcnt(0) (DMA-only counter) + BAR before tile t+1
//   reads => staged data landed. Tail: t=NT-1 stages/gates nothing.
//
// Grid swizzle: per-XCD 8x8 block-squares (64 blocks = 32 CU x 2 = exactly
// one square in flight per XCD) => A+B working set 8 MB/XCD, mostly L2/L3
// resident; each XCD keeps a fixed by-range for panel reuse.
//
// Packed layout UNCHANGED (converters identical to R5-R13): [R,K] bf16 in
// 256-row panels, per K-tile two 16 KiB half-regions (h=0,1) of 16x32
// subtiles, st_16x32 swizzle pre-applied in global memory. A 128-row block
// maps to half h=by&1 of panel by>>1 -- one 16 KiB region per K-tile.
// ---------------------------------------------------------------------------

typedef __bf16 bf16_t;
typedef bf16_t bf16x8 __attribute__((ext_vector_type(8)));
typedef float  floatx4 __attribute__((ext_vector_type(4)));

#define AS1 __attribute__((address_space(1)))
#define AS3 __attribute__((address_space(3)))

__device__ __forceinline__ void async_cp16(const void* g, void* l) {
    __builtin_amdgcn_global_load_lds((const AS1 void*)g, (AS3 void*)l, 16, 0, 0);
}

// tanh-approx gelu: gelu = x * (1 - 1/(1+e^{2u})), u = k0*(x + k1*x^3)
__device__ __forceinline__ float gelu_fast(float x) {
    const float C0 = 1.5957691216057308f;   // 2*sqrt(2/pi)
    const float C1 = 0.0713548163f;         // C0 * 0.044715
    float u2 = x * fmaf(C1, x * x, C0);
    float e  = __expf(u2);
    float r  = __builtin_amdgcn_rcpf(1.0f + e);
    return x * (1.0f - r);
}

// fp32 [R,K] row-major -> packed+swizzled bf16. One thread per 16B chunk.
// tshift = log2(K/64).  (UNCHANGED -- proven through R5-R13.)
__global__ __launch_bounds__(256)
void cvt_pack_swz(const float* __restrict__ src, bf16_t* __restrict__ dst,
                  int K, int tshift)
{
    const size_t   oc = (size_t)blockIdx.x * 256 + threadIdx.x;  // 16B chunk
    const uint32_t ho = ((uint32_t)oc & 1023u) * 16u;  // phys byte in half-tile
    const size_t   region = oc >> 10;                  // 16 KiB half-tile index
    const int      h  = (int)(region & 1);
    const size_t   pt = region >> 1;
    const int      t  = (int)(pt & ((1u << tshift) - 1));
    const size_t   p  = pt >> tshift;
    // physical -> logical (involution)
    const uint32_t L = ho ^ (((ho >> 9) & 1u) << 5);
    const int      s = (int)(L >> 10);                 // subtile 0..15
    const uint32_t u = L & 1023u;
    const size_t   row = p * 256 + (size_t)(h * 128 + (s >> 1) * 16 + (int)(u >> 6));
    const int      k   = (t << 6) + (s & 1) * 32 + (int)((u & 63u) >> 1);
    const float* sp = src + row * (size_t)K + k;
    float4 a = *(const float4*)sp;
    float4 b = *(const float4*)(sp + 4);
    bf16x8 o;
    o[0] = (bf16_t)a.x; o[1] = (bf16_t)a.y; o[2] = (bf16_t)a.z; o[3] = (bf16_t)a.w;
    o[4] = (bf16_t)b.x; o[5] = (bf16_t)b.y; o[6] = (bf16_t)b.z; o[7] = (bf16_t)b.w;
    *(bf16x8*)(dst + oc * 8) = o;
}

// C = A * B^T, A/B packed+swizzled, both staged through LDS. 128x128 tile.
// nsqpx = 8x8 block-squares per XCD; sqxshift = log2(squares along x).
template<bool ACT, typename OutT>
__global__ __launch_bounds__(512, 4)
void gemm128(const bf16_t* __restrict__ A, const bf16_t* __restrict__ B,
             OutT* __restrict__ C, int M, int N, int K,
             int nsqpx, int sqxshift)
{
    __shared__ __align__(16) bf16_t lds[32768];        // 64 KiB
    char* const ldsb = (char*)lds;

    const int NT = K >> 6;                             // K-tiles (BK=64)

    // XCD-aware 8x8 square mapping: each XCD runs one square (64 blocks =
    // 32 CU x 2) at a time; squares of one XCD share the by-range.
    const int j   = blockIdx.x;
    const int xcd = j & 7;
    const int loc = j >> 3;
    const int sq  = loc >> 6;
    const int jj  = loc & 63;
    const int sqg = xcd * nsqpx + sq;
    const int sqy = sqg >> sqxshift;
    const int sqx = sqg & ((1 << sqxshift) - 1);
    const int by  = sqy * 8 + (jj >> 3);
    const int bx  = sqx * 8 + (jj & 7);

    const int tid  = threadIdx.x;
    const int lane = tid & 63;
    const int wave = tid >> 6;
    const int wm = wave >> 1;                          // 0..3: 32-row group
    const int wn = wave & 1;                           // 0..1: 64-col group

    // block = half (by&1) of 256-row panel (by>>1); one 16 KiB region/K-tile
    const bf16_t* const Ap = A + (size_t)(by >> 1) * NT * 16384
                               + (size_t)(by & 1) * 8192;
    const bf16_t* const Bp = B + (size_t)(bx >> 1) * NT * 16384
                               + (size_t)(bx & 1) * 8192;

    // per-lane swizzled frag offset: logical (lane&15)*64 + (lane>>4)*16
    uint32_t lsw = (uint32_t)(((lane & 15) << 6) + ((lane >> 4) << 4));
    lsw ^= ((lsw >> 9) & 1u) << 5;

    floatx4 acc[2][4];
    #pragma unroll
    for (int i = 0; i < 2; ++i)
      #pragma unroll
      for (int jn = 0; jn < 4; ++jn)
        acc[i][jn] = (floatx4)0.0f;

    // stage K-tile t: A region -> buf+0, B region -> buf+16K (4 cp16/thread)
    auto stage = [&](int t) {
        const char* ga = (const char*)(Ap + (size_t)t * 16384);
        const char* gb = (const char*)(Bp + (size_t)t * 16384);
        char* base = ldsb + ((t & 1) << 15);
        async_cp16(ga + tid * 16, base + tid * 16);
        async_cp16(ga + 8192 + tid * 16, base + 8192 + tid * 16);
        async_cp16(gb + tid * 16, base + 16384 + tid * 16);
        async_cp16(gb + 8192 + tid * 16, base + 16384 + 8192 + tid * 16);
    };

    // prologue: stage tile 0, drain, barrier
    stage(0);
    asm volatile("s_waitcnt vmcnt(0)" ::: "memory");
    __builtin_amdgcn_s_barrier();

    for (int t = 0; t < NT; ++t) {
        const bool s1 = (t + 1 < NT);
        if (s1) stage(t + 1);                          // -> other buffer

        const char* aB = ldsb + ((t & 1) << 15);
        const char* bB = aB + 16384;
        bf16x8 af[2][2], bf[4][2];
        #pragma unroll
        for (int fm = 0; fm < 2; ++fm)
          #pragma unroll
          for (int ks = 0; ks < 2; ++ks)
            af[fm][ks] = *(const bf16x8*)(aB + (((((wm << 1) + fm) << 1) + ks) << 10 | lsw));
        #pragma unroll
        for (int fn = 0; fn < 4; ++fn)
          #pragma unroll
          for (int ks = 0; ks < 2; ++ks)
            bf[fn][ks] = *(const bf16x8*)(bB + (((((wn << 2) + fn) << 1) + ks) << 10 | lsw));

        __builtin_amdgcn_s_setprio(1);
        #pragma unroll
        for (int ks = 0; ks < 2; ++ks)
          #pragma unroll
          for (int fm = 0; fm < 2; ++fm)
            #pragma unroll
            for (int fn = 0; fn < 4; ++fn)
              acc[fm][fn] = __builtin_amdgcn_mfma_f32_16x16x32_bf16(
                  af[fm][ks], bf[fn][ks], acc[fm][fn], 0, 0, 0);
        __builtin_amdgcn_s_setprio(0);

        if (s1) asm volatile("s_waitcnt vmcnt(0)" ::: "memory");  // t+1 landed
        __builtin_amdgcn_s_barrier();
    }

    if constexpr (ACT) {
        // Fused quant+gelu; repack into act's packed layout. Block output =
        // 2 act regions: (panel by>>1, ktile bx*2+tau, half by&1), tau=wn.
        // Wave (wm,wn) writes region tau=wn, rows wm*32..+32. 32 KiB in LDS.
        #pragma unroll
        for (int fm = 0; fm < 2; ++fm)
          #pragma unroll
          for (int fn = 0; fn < 4; ++fn)
            #pragma unroll
            for (int r = 0; r < 4; ++r) {
                float h = acc[fm][fn][r];
                float q = rintf(h * 10.0f);             // round half-to-even
                q = fminf(fmaxf(q, -32768.0f), 32767.0f);
                h = gelu_fast(q * 0.1f);
                uint32_t L = ((uint32_t)((((wm << 1) + fm) << 1) + (fn >> 1)) << 10)
                           + (uint32_t)((((lane >> 4) << 2) + r) << 6)
                           + (uint32_t)((((fn & 1) << 4) + (lane & 15)) << 1);
                uint32_t P = L ^ (((L >> 9) & 1u) << 5);
                *(bf16_t*)(ldsb + ((uint32_t)wn << 14) + P) = (bf16_t)h;
            }
        __syncthreads();
        // copyout: 2 regions x 16 KiB, contiguous; 2048 chunks / 512 thr.
        const int nkt2 = N >> 6;
        #pragma unroll
        for (int it = 0; it < 4; ++it) {
            const int ch  = it * 512 + tid;            // 0..2047
            const int tau = ch >> 10;
            const int c   = ch & 1023;
            const size_t gbyte = ((size_t)(by >> 1) * nkt2 + (size_t)(bx * 2 + tau)) * 32768
                               + (size_t)(by & 1) * 16384 + (size_t)c * 16;
            *(bf16x8*)((char*)C + gbyte) = *(const bf16x8*)(ldsb + (size_t)ch * 16);
        }
    } else {
        // Row-major fp32 stores (quarter-wave writes 64B contiguous).
        const int r0 = by * 128 + wm * 32;
        const int c0 = bx * 128 + wn * 64;
        #pragma unroll
        for (int fm = 0; fm < 2; ++fm)
          #pragma unroll
          for (int fn = 0; fn < 4; ++fn) {
            const int col = c0 + fn * 16 + (lane & 15);
            #pragma unroll
            for (int r = 0; r < 4; ++r) {
              const int row = r0 + fm * 16 + ((lane >> 4) << 2) + r;
              C[(size_t)row * N + col] = (OutT)acc[fm][fn][r];
            }
          }
    }
}

extern "C" void kernel_launch(void* const* d_in, const int* in_sizes, int n_in,
                              void* d_out, int out_size, void* d_ws, size_t ws_size,
                              hipStream_t stream)
{
    const int M  = 8192;   // BATCH*SEQ
    const int DM = 2048;   // d_model
    const int DF = 8192;   // d_ff

    const float* x  = (const float*)d_in[0];
    const float* W1 = (const float*)d_in[1];
    const float* W2 = (const float*)d_in[2];
    float* out = (float*)d_out;

    bf16_t* xb  = (bf16_t*)d_ws;                      // packed [M,DM]
    bf16_t* w1b = xb  + (size_t)M  * DM;              // packed [DF,DM]
    bf16_t* w2b = w1b + (size_t)DF * DM;              // packed [DM,DF]
    bf16_t* act = w2b + (size_t)DM * DF;              // packed [M,DF]

    // converters: one thread per 16B output chunk; tshift = log2(K/64)
    cvt_pack_swz<<<8192, 256, 0, stream>>>(x,  xb,  DM, 5);
    cvt_pack_swz<<<8192, 256, 0, stream>>>(W1, w1b, DM, 5);
    cvt_pack_swz<<<8192, 256, 0, stream>>>(W2, w2b, DF, 7);

    // GEMM1 + fused quant/gelu: act = pack(gelu_q(xb @ w1b^T))
    // grid 64x64 = 4096 blocks; squares: 8x8 => nsqpx=8, sqxshift=3
    gemm128<true, bf16_t><<<dim3(4096), 512, 0, stream>>>(
        xb, w1b, act, M, DF, DM, 8, 3);
    // GEMM2: out = act @ w2b^T; grid 16x64 = 1024 blocks;
    // squares: 8(y) x 2(x) = 16 => nsqpx=2, sqxshift=1
    gemm128<false, float><<<dim3(1024), 512, 0, stream>>>(
        act, w2b, out, M, DM, DF, 2, 1);
}